// Round 2
// baseline (2508.813 us; speedup 1.0000x reference)
//
#include <hip/hip_runtime.h>
#include <cmath>

// Problem constants
#define B_ 1024
#define V_ 8192
#define E_ 64
#define H_ 64
#define L_ 16
#define SOS 1
#define EOS 2

typedef float f32x4 __attribute__((ext_vector_type(4)));

// d_out layout (floats), in reference return order:
// output [B,17,V] | seq_lengths [B] | entropy [1] | hidden_state [B,H] | embeds [B,L,E]
#define ONEHOT_OFF 0ull
#define SEQ_OFF    142606336ull
#define ENT_OFF    142607360ull
#define HID_OFF    142607361ull
#define EMB_OFF    142672897ull

// ---------------------------------------------------------------------------
// Init kernel: zero one-hot slab 0 (all rows) + write SOS one-hot + ent=0
// + zero the rendezvous flags (replay-safe: runs inside the graph each time).
// ---------------------------------------------------------------------------
__global__ __launch_bounds__(256) void init_zero_kernel(float* __restrict__ out,
                                                        int* __restrict__ flags)
{
    const int t = threadIdx.x;
    const int row = blockIdx.x;
    float* slab = out + ONEHOT_OFF + (size_t)row * (17 * 8192);  // slot 0
#pragma unroll
    for (int j = 0; j < 8; ++j) {
        f32x4 z = {0.f, 0.f, 0.f, 0.f};
        if (j == 0 && t == 0) z.y = 1.0f;   // v=1 == SOS
        __builtin_nontemporal_store(z, (f32x4*)(slab + j * 1024 + t * 4));
    }
    if (row == 0 && t == 1) out[ENT_OFF] = 0.f;
    if (row == 1) flags[t] = 0;            // 256 >= 64*16 padded flags? (1024 ints: 4 rows)
    if (row == 2) flags[256 + t] = 0;
    if (row == 3) flags[512 + t] = 0;
    if (row == 4) flags[768 + t] = 0;
}

// ---------------------------------------------------------------------------
// Persistent fused kernel. Grid: 512 blocks = 64 row-groups (rg, 16 rows) x
// 8 v-splits (vs, 1024 v). 2 blocks/CU guaranteed by launch_bounds + LDS.
// Per step: phase A = logits GEMM + online stats + argmax partials (+fused
// zero-fill of next one-hot slab); rendezvous among the 8 blocks of the rg;
// phase B = combine partials (redundant per block) -> token/ent/seq, emb
// gather, gates-slice GEMM (vs owns 8 of 64 h-units), LSTM, h exchange via
// global hx + second rendezvous. h state lives in LDS (X) block-locally.
// ---------------------------------------------------------------------------
__global__ __launch_bounds__(256, 2) void fused_kernel(
    const float* __restrict__ emb_table,
    const float* __restrict__ W_ih, const float* __restrict__ W_hh,
    const float* __restrict__ b_ih, const float* __restrict__ b_hh,
    const float* __restrict__ hidden_in,
    const float* __restrict__ Wout, const float* __restrict__ bout,
    const float* __restrict__ gumbels,
    float* __restrict__ pm, float* __restrict__ pS, float* __restrict__ pT,
    float* __restrict__ pbv, int* __restrict__ pbi,
    float* __restrict__ hx,          // [64 rg][8 vs][16 row][8 unit]
    int* __restrict__ flags,         // [64 rg][16 pad]
    float* __restrict__ out)
{
    __shared__ float wV[256][64];   // W_out chunk (GEMM) / aliased Wg[32][128] (gates)
    __shared__ float X[16][132];    // [row][emb 0..63 | h 64..127], pad 132
    __shared__ int   tokL[16];
    __shared__ float entL[16];
    __shared__ int   seqL[16];

    const int t  = threadIdx.x;
    const int rg = blockIdx.x >> 3;
    const int vs = blockIdx.x & 7;
    const int rowBase = rg * 16;
    const int tv = t & 63;            // lane
    const int tr = t >> 6;            // wave id = row-quad
    const int r0 = tr * 4;

    // wV staging geometry (XOR chunk-swizzle, neutral but kept)
    const int srow = t >> 4;                 // 0..15
    const int scc  = t & 15;                 // source 16B chunk
    const int sdst = ((scc ^ srow) << 2);    // swizzled column (floats)

    float c_reg = 0.f;                // LSTM cell state for (row=t>>3, unit=vs*8+(t&7)), t<128
    int sync_ev = 0;

    auto rg_sync = [&]() {
        __syncthreads();
        ++sync_ev;
        if (t == 0) {
            __hip_atomic_fetch_add(&flags[rg * 16], 1, __ATOMIC_RELEASE,
                                   __HIP_MEMORY_SCOPE_AGENT);
            while (__hip_atomic_load(&flags[rg * 16], __ATOMIC_ACQUIRE,
                                     __HIP_MEMORY_SCOPE_AGENT) < 8 * sync_ev)
                __builtin_amdgcn_s_sleep(2);
        }
        __syncthreads();
    };

    // gates-slice GEMM + LSTM + hx write + exchange; X emb/h halves must be staged.
    auto gates_lstm = [&]() {
        // stage Wg[32][128] = rows {g*64+vs*8+ul | g<4, ul<8} of [W_ih|W_hh], aliased over wV
        float* Wg = &wV[0][0];
#pragma unroll
        for (int q = 0; q < 4; ++q) {
            const int idx = (q * 256 + t) * 4;      // 0..4095
            const int gr = idx >> 7;                // 0..31
            const int k  = idx & 127;
            const int g = gr >> 3, ul = gr & 7;
            const int wrow = g * 64 + vs * 8 + ul;
            const float* src = (k < 64) ? (W_ih + (size_t)wrow * 64 + k)
                                        : (W_hh + (size_t)wrow * 64 + (k - 64));
            *(float4*)(Wg + gr * 128 + k) = *(const float4*)src;
        }
        __syncthreads();
        if (t < 128) {
            const int row = t >> 3, ul = t & 7;
            const int unit = vs * 8 + ul;
            float a0 = b_ih[unit]       + b_hh[unit];         // i
            float a1 = b_ih[64 + unit]  + b_hh[64 + unit];    // f
            float a2 = b_ih[128 + unit] + b_hh[128 + unit];   // g
            float a3 = b_ih[192 + unit] + b_hh[192 + unit];   // o
            for (int k4 = 0; k4 < 32; ++k4) {
                const float4 x4 = *(const float4*)&X[row][k4 * 4];
                const float4 w0 = *(const float4*)(Wg + (0 * 8 + ul) * 128 + k4 * 4);
                const float4 w1 = *(const float4*)(Wg + (1 * 8 + ul) * 128 + k4 * 4);
                const float4 w2 = *(const float4*)(Wg + (2 * 8 + ul) * 128 + k4 * 4);
                const float4 w3 = *(const float4*)(Wg + (3 * 8 + ul) * 128 + k4 * 4);
                a0 += x4.x * w0.x + x4.y * w0.y + x4.z * w0.z + x4.w * w0.w;
                a1 += x4.x * w1.x + x4.y * w1.y + x4.z * w1.z + x4.w * w1.w;
                a2 += x4.x * w2.x + x4.y * w2.y + x4.z * w2.z + x4.w * w2.w;
                a3 += x4.x * w3.x + x4.y * w3.y + x4.z * w3.z + x4.w * w3.w;
            }
            const float si = 1.f / (1.f + expf(-a0));
            const float sf = 1.f / (1.f + expf(-a1));
            const float so = 1.f / (1.f + expf(-a3));
            const float cn = sf * c_reg + si * tanhf(a2);
            const float hn = so * tanhf(cn);
            c_reg = cn;
            hx[((size_t)(rg * 8 + vs) * 16 + row) * 8 + ul] = hn;
        }
        rg_sync();
        // gather full h row-slices -> X h-half
        {
            const int row = t >> 4, k0 = (t & 15) * 4;
            const int vsp = k0 >> 3, off = k0 & 7;
            float4 hv = *(const float4*)(hx + ((size_t)(rg * 8 + vsp) * 16 + row) * 8 + off);
            *(float4*)&X[row][64 + k0] = hv;
        }
        __syncthreads();
    };

    // ---------------- prologue: step -1 (SOS embed, h0 = hidden_in, c0 = 0) ----
    {
        const int row = t >> 4, k0 = (t & 15) * 4;
        float4 evv = *(const float4*)(emb_table + (size_t)SOS * 64 + k0);
        *(float4*)&X[row][k0] = evv;
        if (vs == 0) {
            const size_t eo = EMB_OFF + ((size_t)(rowBase + row) * 16 + 0) * 64 + k0;
            out[eo + 0] = evv.x; out[eo + 1] = evv.y; out[eo + 2] = evv.z; out[eo + 3] = evv.w;
        }
        float4 hv = *(const float4*)(hidden_in + (size_t)(rowBase + row) * 64 + k0);
        *(float4*)&X[row][64 + k0] = hv;
    }
    __syncthreads();
    gates_lstm();                    // produces h(0) in X h-half

    // ---------------- main loop ------------------------------------------------
    for (int i = 0; i < 16; ++i) {
        const float* gstep = gumbels + (size_t)i * 8388608ull;   // i*B*V

        // ---- phase A: logits + stats + argmax partials + zero-fill slab(i+1) --
        {
            const f32x4 z = {0.f, 0.f, 0.f, 0.f};
            const size_t slab = ONEHOT_OFF + (size_t)(i + 1) * 8192 + (size_t)(vs * 1024 + t * 4);
#pragma unroll
            for (int r = 0; r < 16; ++r) {
                __builtin_nontemporal_store(z,
                    (f32x4*)(out + (size_t)(rowBase + r) * (17 * 8192) + slab));
            }
        }

        float m[4], S[4], T[4], bv[4];
        int   bi[4];
#pragma unroll
        for (int r = 0; r < 4; ++r) {
            m[r] = -INFINITY; S[r] = 0.f; T[r] = 0.f; bv[r] = -INFINITY; bi[r] = 0;
        }

        for (int cc = 0; cc < 4; ++cc) {
            const int vglob = vs * 1024 + cc * 256;

            float gv[16], bo[4];
#pragma unroll
            for (int j = 0; j < 4; ++j) {
                const int v = vglob + 64 * j + tv;
                bo[j] = bout[v];
#pragma unroll
                for (int r = 0; r < 4; ++r)
                    gv[j * 4 + r] = gstep[(size_t)(rowBase + r0 + r) * V_ + v];
            }

            __syncthreads();   // previous chunk's compute / phase-B LDS use done
#pragma unroll
            for (int j = 0; j < 16; ++j) {           // stage 256x64 W_out chunk
                const int vl = srow + 16 * j;
                float4 w = *(const float4*)(Wout + (size_t)(vglob + vl) * 64 + scc * 4);
                *(float4*)&wV[vl][sdst] = w;
            }
            __syncthreads();

            float acc[4][4];
#pragma unroll
            for (int r = 0; r < 4; ++r)
#pragma unroll
                for (int j = 0; j < 4; ++j) acc[r][j] = 0.f;

#pragma unroll 4
            for (int k4 = 0; k4 < 16; ++k4) {
                const int ks = ((k4 ^ (tv & 15)) << 2);   // swizzled column
                float4 wv[4], hv[4];
#pragma unroll
                for (int j = 0; j < 4; ++j) wv[j] = *(const float4*)&wV[tv + 64 * j][ks];
#pragma unroll
                for (int r = 0; r < 4; ++r) hv[r] = *(const float4*)&X[r0 + r][64 + k4 * 4];
#pragma unroll
                for (int r = 0; r < 4; ++r)
#pragma unroll
                    for (int j = 0; j < 4; ++j)
                        acc[r][j] += hv[r].x * wv[j].x + hv[r].y * wv[j].y +
                                     hv[r].z * wv[j].z + hv[r].w * wv[j].w;
            }

#pragma unroll
            for (int j = 0; j < 4; ++j) {
                const int v  = vglob + 64 * j + tv;
#pragma unroll
                for (int r = 0; r < 4; ++r) {
                    const float l = acc[r][j] + bo[j];
                    const float s = l + gv[j * 4 + r];
                    if (s > bv[r]) { bv[r] = s; bi[r] = v; }   // strict > keeps lowest v
                    const float mn = fmaxf(m[r], l);
                    const float e  = __expf(-fabsf(l - m[r])); // exp(-inf)=0 first time
                    const bool nw  = l > m[r];
                    const float a  = nw ? e : 1.f;
                    const float b2 = nw ? 1.f : e;
                    S[r] = S[r] * a + b2;
                    T[r] = T[r] * a + l * b2;
                    m[r] = mn;
                }
            }
        }

        // wave-64 butterfly reduction across lanes (each wave = 4 rows)
#pragma unroll
        for (int off = 1; off < 64; off <<= 1) {
#pragma unroll
            for (int r = 0; r < 4; ++r) {
                const float mo  = __shfl_xor(m[r], off);
                const float So  = __shfl_xor(S[r], off);
                const float To  = __shfl_xor(T[r], off);
                const float bvo = __shfl_xor(bv[r], off);
                const int   bio = __shfl_xor(bi[r], off);
                const float mn = fmaxf(m[r], mo);
                const float ea = __expf(m[r] - mn);
                const float eb = __expf(mo - mn);
                S[r] = S[r] * ea + So * eb;
                T[r] = T[r] * ea + To * eb;
                m[r] = mn;
                if (bvo > bv[r] || (bvo == bv[r] && bio < bi[r])) { bv[r] = bvo; bi[r] = bio; }
            }
        }
        if (tv == 0) {
#pragma unroll
            for (int r = 0; r < 4; ++r) {
                const int row = rowBase + r0 + r;
                const int o = vs * 1024 + row;
                pm[o] = m[r]; pS[o] = S[r]; pT[o] = T[r]; pbv[o] = bv[r]; pbi[o] = bi[r];
            }
        }
        rg_sync();   // all 8 v-splits' partials visible

        // ---- phase B: combine (redundant per block) ---------------------------
        if (t < 16) {
            const int row = rowBase + t;
            float m2 = -INFINITY, S2 = 0.f, T2 = 0.f, bv2 = -INFINITY; int bi2 = 0;
            for (int s = 0; s < 8; ++s) {   // ascending split = ascending v
                const int o = s * 1024 + row;
                const float ms = pm[o], Ss = pS[o], Ts = pT[o], bvs = pbv[o];
                const int bis = pbi[o];
                const float mn = fmaxf(m2, ms);
                const float ea = __expf(m2 - mn), eb = __expf(ms - mn);
                S2 = S2 * ea + Ss * eb; T2 = T2 * ea + Ts * eb; m2 = mn;
                if (bvs > bv2 || (bvs == bv2 && bis < bi2)) { bv2 = bvs; bi2 = bis; }
            }
            const float lse  = m2 + logf(S2);
            const float entc = lse - T2 / S2;
            const int tok = bi2;
            if (vs == 0)
                out[ONEHOT_OFF + (size_t)row * (17 * 8192) + (size_t)(i + 1) * 8192 + tok] = 1.0f;
            const float ev = (i == 0) ? entc : (entL[t] + entc);
            entL[t] = ev;
            int sl = (i == 0) ? (L_ + 1) : seqL[t];
            if (tok == EOS && sl == (L_ + 1)) sl = i + 2;  // (max_pred==1.0 always)
            seqL[t] = sl;
            tokL[t] = tok;
            if (i == 15 && vs == 0) out[SEQ_OFF + row] = (float)sl;
        }
        __syncthreads();

        if (i == 15) {
            if (vs == 0 && t == 0) {
                float a = 0.f, b = 0.f;
                for (int r = 0; r < 8; ++r)  a += entL[r];
                for (int r = 8; r < 16; ++r) b += entL[r];
                atomicAdd(out + ENT_OFF, a * (1.0f / (1024.0f * 16.0f)));
                atomicAdd(out + ENT_OFF, b * (1.0f / (1024.0f * 16.0f)));
            }
            break;
        }

        // emb gather for token(i) -> X emb-half, + embeds output (vs==0)
        {
            const int row = t >> 4, k0 = (t & 15) * 4;
            const int tk = tokL[row];
            float4 evv = *(const float4*)(emb_table + (size_t)tk * 64 + k0);
            *(float4*)&X[row][k0] = evv;
            if (vs == 0) {
                const size_t eo = EMB_OFF + ((size_t)(rowBase + row) * 16 + (size_t)(i + 1)) * 64 + k0;
                out[eo + 0] = evv.x; out[eo + 1] = evv.y; out[eo + 2] = evv.z; out[eo + 3] = evv.w;
            }
        }
        __syncthreads();

        gates_lstm();    // h(i+1) in X h-half (includes rendezvous + final sync)
    }
}

extern "C" void kernel_launch(void* const* d_in, const int* in_sizes, int n_in,
                              void* d_out, int out_size, void* d_ws, size_t ws_size,
                              hipStream_t stream) {
    (void)in_sizes; (void)ws_size; (void)out_size;
    if (n_in < 9) return;
    const float* hidden    = (const float*)d_in[0];
    const float* embedding = (const float*)d_in[1];
    const float* W_ih      = (const float*)d_in[2];
    const float* W_hh      = (const float*)d_in[3];
    const float* b_ih      = (const float*)d_in[4];
    const float* b_hh      = (const float*)d_in[5];
    const float* W_out     = (const float*)d_in[6];
    const float* b_out     = (const float*)d_in[7];
    const float* gumbels   = (const float*)d_in[8];
    float* out = (float*)d_out;

    // workspace: pm/pS/pT/pbv/pbi [8x1024 each] | hx [64*8*16*8] | flags [1024 ints]
    float* wsf = (float*)d_ws;
    float* pm  = wsf;
    float* pS  = pm + 8192;
    float* pT  = pS + 8192;
    float* pbv = pT + 8192;
    int*   pbi = (int*)(pbv + 8192);
    float* hx  = wsf + 40960;
    int*   flags = (int*)(wsf + 40960 + 65536);

    (void)hipMemcpyAsync(out + HID_OFF, hidden, (size_t)B_ * H_ * sizeof(float),
                         hipMemcpyDeviceToDevice, stream);
    init_zero_kernel<<<1024, 256, 0, stream>>>(out, flags);

    fused_kernel<<<512, 256, 0, stream>>>(embedding, W_ih, W_hh, b_ih, b_hh,
        hidden, W_out, b_out, gumbels, pm, pS, pT, pbv, pbi, hx, flags, out);
}